// Round 4
// baseline (626.034 us; speedup 1.0000x reference)
//
#include <hip/hip_runtime.h>

typedef __bf16 bf16;
typedef bf16 bf16x2 __attribute__((ext_vector_type(2)));
typedef bf16 bf16x8 __attribute__((ext_vector_type(8)));
typedef float f32x4 __attribute__((ext_vector_type(4)));

#define B_ 4
#define T_ 4096
#define H_ 16
#define DK_ 64
#define DV_ 64
#define DMODEL_ 1024
#define M_ (B_ * T_)   // 16384
#define EPS_ 1e-6f

__device__ __forceinline__ void async_ld16(const void* g, void* l) {
    __builtin_amdgcn_global_load_lds(
        (const __attribute__((address_space(1))) unsigned int*)g,
        (__attribute__((address_space(3))) unsigned int*)l,
        16, 0, 0);
}

// ------------------------------------------- transpose + fp32->bf16 convert
struct TPtrs { const float* s[4]; bf16* d[4]; };

__global__ void transpose4(TPtrs p) {
    __shared__ bf16 t[32][33];
    const float* src = p.s[blockIdx.z];
    bf16*        dst = p.d[blockIdx.z];
    const int tx = threadIdx.x, ty = threadIdx.y;
    const int x  = blockIdx.x * 32 + tx;
    const int y0 = blockIdx.y * 32 + ty;
#pragma unroll
    for (int i = 0; i < 32; i += 8)
        t[ty + i][tx] = (bf16)src[(size_t)(y0 + i) * 1024 + x];
    __syncthreads();
    const int xo = blockIdx.y * 32 + tx;   // k index
    const int yo = blockIdx.x * 32 + ty;   // n index
#pragma unroll
    for (int i = 0; i < 32; i += 8)
        dst[(size_t)(yo + i) * 1024 + xo] = t[tx][ty + i];
}

// ---------------------------------------------------- GEMM, A = fp32 global
// C[M,N] = act(A[M,K] @ Bt[N,K]^T + bias[N]); act=1 -> phi(x)=elu(x)+1
__global__ __launch_bounds__(256) void gemm_f32a_kernel(
    const float* __restrict__ A, const bf16* __restrict__ Bt,
    const float* __restrict__ bias, bf16* __restrict__ C,
    int M, int N, int K, int act)
{
    __shared__ bf16 As[128 * 32];
    __shared__ bf16 Bs[128 * 32];

    const int tid  = threadIdx.x;
    const int wave = tid >> 6;
    const int lane = tid & 63;
    const int m0 = blockIdx.y * 128;
    const int n0 = blockIdx.x * 128;
    const int wm = (wave >> 1) * 64;
    const int wn = (wave & 1) * 64;
    const int fr = lane & 15;
    const int fk = (lane >> 4) * 8;

    f32x4 acc[4][4] = {};

    const int c0 = wave * 64 + lane;
    const int c1 = c0 + 256;
    const bf16* gB0 = Bt + (size_t)(n0 + (c0 >> 2)) * K + (c0 & 3) * 8;
    const bf16* gB1 = Bt + (size_t)(n0 + (c1 >> 2)) * K + (c1 & 3) * 8;
    char* lB0 = (char*)Bs + (size_t)(wave * 64) * 16;
    char* lB1 = lB0 + 4096;

    const int ar = tid >> 1;
    const int ak = (tid & 1) * 16;
    const float* gA = A + (size_t)(m0 + ar) * K + ak;

    for (int kt = 0; kt < K; kt += 32) {
        async_ld16(gB0 + kt, lB0);
        async_ld16(gB1 + kt, lB1);
        float4 f0 = *(const float4*)(gA + kt);
        float4 f1 = *(const float4*)(gA + kt + 4);
        float4 f2 = *(const float4*)(gA + kt + 8);
        float4 f3 = *(const float4*)(gA + kt + 12);
        bf16x8 h0, h1;
        h0[0] = (bf16)f0.x; h0[1] = (bf16)f0.y; h0[2] = (bf16)f0.z; h0[3] = (bf16)f0.w;
        h0[4] = (bf16)f1.x; h0[5] = (bf16)f1.y; h0[6] = (bf16)f1.z; h0[7] = (bf16)f1.w;
        h1[0] = (bf16)f2.x; h1[1] = (bf16)f2.y; h1[2] = (bf16)f2.z; h1[3] = (bf16)f2.w;
        h1[4] = (bf16)f3.x; h1[5] = (bf16)f3.y; h1[6] = (bf16)f3.z; h1[7] = (bf16)f3.w;
        *(bf16x8*)&As[ar * 32 + ak]     = h0;
        *(bf16x8*)&As[ar * 32 + ak + 8] = h1;
        __syncthreads();
        bf16x8 af[4], bfr[4];
#pragma unroll
        for (int i = 0; i < 4; ++i)
            af[i] = *(const bf16x8*)&As[(wm + i * 16 + fr) * 32 + fk];
#pragma unroll
        for (int j = 0; j < 4; ++j)
            bfr[j] = *(const bf16x8*)&Bs[(wn + j * 16 + fr) * 32 + fk];
#pragma unroll
        for (int i = 0; i < 4; ++i)
#pragma unroll
            for (int j = 0; j < 4; ++j)
                acc[i][j] = __builtin_amdgcn_mfma_f32_16x16x32_bf16(
                    af[i], bfr[j], acc[i][j], 0, 0, 0);
        __syncthreads();
    }

#pragma unroll
    for (int j = 0; j < 4; ++j) {
        const int col = n0 + wn + j * 16 + fr;
        const float bb = bias[col];
#pragma unroll
        for (int i = 0; i < 4; ++i) {
            const int row = m0 + wm + i * 16 + (lane >> 4) * 4;
#pragma unroll
            for (int r = 0; r < 4; ++r) {
                float x = acc[i][j][r] + bb;
                if (act) x = (x > 0.0f) ? (x + 1.0f) : __expf(x);
                C[(size_t)(row + r) * N + col] = (bf16)x;
            }
        }
    }
}

// ------------------------------------- GEMM, A = bf16 global, OUTPUT = fp32
__global__ __launch_bounds__(256) void gemm_bt_f32out_kernel(
    const bf16* __restrict__ A, const bf16* __restrict__ Bt,
    const float* __restrict__ bias, float* __restrict__ C,
    int M, int N, int K)
{
    __shared__ bf16 As[128 * 32];
    __shared__ bf16 Bs[128 * 32];

    const int tid  = threadIdx.x;
    const int wave = tid >> 6;
    const int lane = tid & 63;
    const int m0 = blockIdx.y * 128;
    const int n0 = blockIdx.x * 128;
    const int wm = (wave >> 1) * 64;
    const int wn = (wave & 1) * 64;
    const int fr = lane & 15;
    const int fk = (lane >> 4) * 8;

    f32x4 acc[4][4] = {};

    const int c0 = wave * 64 + lane;
    const int c1 = c0 + 256;
    const int rA0 = c0 >> 2, kA0 = (c0 & 3) * 8;
    const int rA1 = c1 >> 2, kA1 = (c1 & 3) * 8;
    const bf16* gA0 = A  + (size_t)(m0 + rA0) * K + kA0;
    const bf16* gA1 = A  + (size_t)(m0 + rA1) * K + kA1;
    const bf16* gB0 = Bt + (size_t)(n0 + rA0) * K + kA0;
    const bf16* gB1 = Bt + (size_t)(n0 + rA1) * K + kA1;
    char* lA0 = (char*)As + (size_t)(wave * 64) * 16;
    char* lA1 = lA0 + 4096;
    char* lB0 = (char*)Bs + (size_t)(wave * 64) * 16;
    char* lB1 = lB0 + 4096;

    for (int kt = 0; kt < K; kt += 32) {
        async_ld16(gA0 + kt, lA0);
        async_ld16(gA1 + kt, lA1);
        async_ld16(gB0 + kt, lB0);
        async_ld16(gB1 + kt, lB1);
        __syncthreads();
        bf16x8 af[4], bfr[4];
#pragma unroll
        for (int i = 0; i < 4; ++i)
            af[i] = *(const bf16x8*)&As[(wm + i * 16 + fr) * 32 + fk];
#pragma unroll
        for (int j = 0; j < 4; ++j)
            bfr[j] = *(const bf16x8*)&Bs[(wn + j * 16 + fr) * 32 + fk];
#pragma unroll
        for (int i = 0; i < 4; ++i)
#pragma unroll
            for (int j = 0; j < 4; ++j)
                acc[i][j] = __builtin_amdgcn_mfma_f32_16x16x32_bf16(
                    af[i], bfr[j], acc[i][j], 0, 0, 0);
        __syncthreads();
    }

#pragma unroll
    for (int j = 0; j < 4; ++j) {
        const int col = n0 + wn + j * 16 + fr;
        const float bb = bias[col];
#pragma unroll
        for (int i = 0; i < 4; ++i) {
            const int row = m0 + wm + i * 16 + (lane >> 4) * 4;
#pragma unroll
            for (int r = 0; r < 4; ++r)
                C[(size_t)(row + r) * N + col] = acc[i][j][r] + bb;
        }
    }
}

// -------------------------------------------------- kv partial accumulation
__global__ __launch_bounds__(256) void kv_partial_kernel(
    const bf16* __restrict__ Kb, const bf16* __restrict__ V,
    float* __restrict__ kv_part, float* __restrict__ ksum_part)
{
    const int bh = blockIdx.y;
    const int b  = bh >> 4;
    const int h  = bh & 15;
    const int tc = blockIdx.x;
    const int TC = T_ / 8;           // 512
    const int t0 = tc * TC;

    __shared__ float kb[8][64];
    __shared__ float vb[8][64];

    const int tid = threadIdx.x;
    const int dvq = tid >> 4;
    const int dkq = tid & 15;
    const int lr  = tid >> 5;
    const int lc  = (tid & 31) << 1;

    float acc[4][4] = {};
    float ksacc = 0.0f;

    for (int tt0 = 0; tt0 < TC; tt0 += 8) {
        const size_t base = ((size_t)(b * T_) + t0 + tt0 + lr) * 1024 + h * 64 + lc;
        bf16x2 k2 = *(const bf16x2*)&Kb[base];
        bf16x2 v2 = *(const bf16x2*)&V[base];
        kb[lr][lc] = (float)k2[0]; kb[lr][lc + 1] = (float)k2[1];
        vb[lr][lc] = (float)v2[0]; vb[lr][lc + 1] = (float)v2[1];
        __syncthreads();
#pragma unroll
        for (int tt = 0; tt < 8; ++tt) {
            float4 vv = *(const float4*)&vb[tt][dvq * 4];
            float4 kk = *(const float4*)&kb[tt][dkq * 4];
            float va[4] = {vv.x, vv.y, vv.z, vv.w};
            float ka[4] = {kk.x, kk.y, kk.z, kk.w};
#pragma unroll
            for (int i = 0; i < 4; ++i)
#pragma unroll
                for (int j = 0; j < 4; ++j)
                    acc[i][j] += va[i] * ka[j];
        }
        if (tid < 64) {
#pragma unroll
            for (int tt = 0; tt < 8; ++tt) ksacc += kb[tt][tid];
        }
        __syncthreads();
    }

    float* kvp = kv_part + ((size_t)tc * 64 + bh) * 4096;
#pragma unroll
    for (int i = 0; i < 4; ++i) {
        float4 w = make_float4(acc[i][0], acc[i][1], acc[i][2], acc[i][3]);
        *(float4*)&kvp[(dvq * 4 + i) * 64 + dkq * 4] = w;
    }
    if (tid < 64)
        ksum_part[((size_t)tc * 64 + bh) * 64 + tid] = ksacc;
}

// ------------------------------------------------------------- kv reduction
__global__ __launch_bounds__(256) void kv_reduce_kernel(
    const float* __restrict__ kv_part, const float* __restrict__ ksum_part,
    bf16* __restrict__ kvb, float* __restrict__ ksum)
{
    const int bh = blockIdx.x;
    const int tid = threadIdx.x;
    for (int e = tid; e < 4096; e += 256) {
        float s = 0.0f;
#pragma unroll
        for (int tc = 0; tc < 8; ++tc)
            s += kv_part[((size_t)tc * 64 + bh) * 4096 + e];
        kvb[(size_t)bh * 4096 + e] = (bf16)s;
    }
    if (tid < 64) {
        float s = 0.0f;
#pragma unroll
        for (int tc = 0; tc < 8; ++tc)
            s += ksum_part[((size_t)tc * 64 + bh) * 64 + tid];
        ksum[bh * 64 + tid] = s;
    }
}

// ------------------------------------------------------------------ attn
__global__ __launch_bounds__(256) void attn_kernel(
    const bf16* __restrict__ Q, const bf16* __restrict__ kvb,
    const float* __restrict__ ksum, bf16* __restrict__ attn)
{
    const int bh = blockIdx.y;
    const int b  = bh >> 4;
    const int h  = bh & 15;
    const int t0 = blockIdx.x * 128;

    __shared__ bf16 As[128 * 64];
    __shared__ bf16 Bs[64 * 64];
    __shared__ float ksum_s[64];
    __shared__ float norm_s[128];

    const int tid  = threadIdx.x;
    const int wave = tid >> 6;
    const int lane = tid & 63;

    const bf16* Qbase = Q + ((size_t)(b * T_) + t0) * 1024 + h * 64;

#pragma unroll
    for (int r2 = 0; r2 < 4; ++r2) {
        const int c   = r2 * 256 + wave * 64 + lane;
        const int row = c >> 3;
        const int ko  = (c & 7) * 8;
        char* l = (char*)As + (size_t)(r2 * 256 + wave * 64) * 16;
        async_ld16(Qbase + (size_t)row * 1024 + ko, l);
    }
    {
        const float4* src = (const float4*)(kvb + (size_t)bh * 4096);
        float4* dst = (float4*)Bs;
        for (int e = tid; e < 512; e += 256) dst[e] = src[e];
    }
    if (tid < 64) ksum_s[tid] = ksum[bh * 64 + tid];
    __syncthreads();

    if (tid < 128) {
        const bf16x8* qp = (const bf16x8*)(Qbase + (size_t)tid * 1024);
        float s = 0.0f;
#pragma unroll
        for (int u = 0; u < 8; ++u) {
            bf16x8 v = qp[u];
#pragma unroll
            for (int e = 0; e < 8; ++e) s += (float)v[e] * ksum_s[u * 8 + e];
        }
        norm_s[tid] = 1.0f / (s + EPS_);
    }
    __syncthreads();

    const int fr  = lane & 15;
    const int fkq = lane >> 4;
    f32x4 acc[2][4] = {};
#pragma unroll
    for (int ks = 0; ks < 2; ++ks) {
        bf16x8 af[2], bfr[4];
#pragma unroll
        for (int i = 0; i < 2; ++i)
            af[i] = *(const bf16x8*)&As[(wave * 32 + i * 16 + fr) * 64 + ks * 32 + fkq * 8];
#pragma unroll
        for (int j = 0; j < 4; ++j)
            bfr[j] = *(const bf16x8*)&Bs[(j * 16 + fr) * 64 + ks * 32 + fkq * 8];
#pragma unroll
        for (int i = 0; i < 2; ++i)
#pragma unroll
            for (int j = 0; j < 4; ++j)
                acc[i][j] = __builtin_amdgcn_mfma_f32_16x16x32_bf16(
                    af[i], bfr[j], acc[i][j], 0, 0, 0);
    }

    bf16* out = attn + ((size_t)(b * T_) + t0) * 1024 + h * 64;
#pragma unroll
    for (int i = 0; i < 2; ++i)
#pragma unroll
        for (int j = 0; j < 4; ++j)
#pragma unroll
            for (int r = 0; r < 4; ++r) {
                const int row = wave * 32 + i * 16 + fkq * 4 + r;
                const int col = j * 16 + fr;
                out[(size_t)row * 1024 + col] = (bf16)(acc[i][j][r] * norm_s[row]);
            }
}

// ---------------------------------------------------------------- launcher
// inputs fp32, OUTPUT fp32 (64 MiB). ws (<=41 MiB): [0,8) WT bf16 |
// [8,40) BIG (K-proj then ATTN, bf16) | 40+ kvb (512K) + ksum (16K).
// d_out doubles as scratch: [0,32 MiB) V-proj then Q-proj (bf16);
// [36,44) kv_part fp32; [44,+128K) ksum_part. Final GEMM overwrites all.
extern "C" void kernel_launch(void* const* d_in, const int* in_sizes, int n_in,
                              void* d_out, int out_size, void* d_ws, size_t ws_size,
                              hipStream_t stream) {
    const float* query = (const float*)d_in[0];
    const float* key_  = (const float*)d_in[1];
    const float* value = (const float*)d_in[2];
    const float* Wq = (const float*)d_in[3];
    const float* bq = (const float*)d_in[4];
    const float* Wk = (const float*)d_in[5];
    const float* bk = (const float*)d_in[6];
    const float* Wv = (const float*)d_in[7];
    const float* bv = (const float*)d_in[8];
    const float* Wo = (const float*)d_in[9];
    const float* bo = (const float*)d_in[10];

    char* ws = (char*)d_ws;
    char* out8 = (char*)d_out;
    const size_t MB = 1024 * 1024;
    bf16* WqT = (bf16*)(ws + 0 * MB);
    bf16* WkT = (bf16*)(ws + 2 * MB);
    bf16* WvT = (bf16*)(ws + 4 * MB);
    bf16* WoT = (bf16*)(ws + 6 * MB);
    bf16* BIG = (bf16*)(ws + 8 * MB);                    // 32 MiB: KB then ATTN
    bf16*  kvb  = (bf16*)(ws + 40 * MB);                 // 512 KiB
    float* ksum = (float*)(ws + 40 * MB + 512 * 1024);   // 16 KiB

    bf16* KB   = BIG;
    bf16* VB   = (bf16*)out8;                            // [0,32 MiB)
    bf16* Qb   = (bf16*)out8;                            // reused after kv
    float* kv_part   = (float*)(out8 + 36 * MB);         // 8 MiB
    float* ksum_part = (float*)(out8 + 44 * MB);         // 128 KiB
    bf16* ATTN = BIG;

    TPtrs tp;
    tp.s[0] = Wq;  tp.s[1] = Wk;  tp.s[2] = Wv;  tp.s[3] = Wo;
    tp.d[0] = WqT; tp.d[1] = WkT; tp.d[2] = WvT; tp.d[3] = WoT;
    transpose4<<<dim3(32, 32, 4), dim3(32, 8, 1), 0, stream>>>(tp);

    gemm_f32a_kernel<<<dim3(8, 128), 256, 0, stream>>>(key_,  WkT, bk, KB, M_, 1024, 1024, 1);
    gemm_f32a_kernel<<<dim3(8, 128), 256, 0, stream>>>(value, WvT, bv, VB, M_, 1024, 1024, 0);

    kv_partial_kernel<<<dim3(8, 64), 256, 0, stream>>>(KB, VB, kv_part, ksum_part);
    kv_reduce_kernel<<<dim3(64), 256, 0, stream>>>(kv_part, ksum_part, kvb, ksum);

    gemm_f32a_kernel<<<dim3(8, 128), 256, 0, stream>>>(query, WqT, bq, Qb, M_, 1024, 1024, 1);

    attn_kernel<<<dim3(32, 64), 256, 0, stream>>>(Qb, kvb, ksum, ATTN);

    gemm_bt_f32out_kernel<<<dim3(8, 128), 256, 0, stream>>>(ATTN, WoT, bo, (float*)d_out, M_, 1024, 1024);
}

// Round 5
// 558.328 us; speedup vs baseline: 1.1213x; 1.1213x over previous
//
#include <hip/hip_runtime.h>

typedef __bf16 bf16;
typedef bf16 bf16x2 __attribute__((ext_vector_type(2)));
typedef bf16 bf16x8 __attribute__((ext_vector_type(8)));
typedef float f32x4 __attribute__((ext_vector_type(4)));

#define B_ 4
#define T_ 4096
#define H_ 16
#define DK_ 64
#define DV_ 64
#define DMODEL_ 1024
#define M_ (B_ * T_)   // 16384
#define EPS_ 1e-6f

__device__ __forceinline__ void async_ld16(const void* g, void* l) {
    __builtin_amdgcn_global_load_lds(
        (const __attribute__((address_space(1))) unsigned int*)g,
        (__attribute__((address_space(3))) unsigned int*)l,
        16, 0, 0);
}

// ------------------------------------------- transpose + fp32->bf16 convert
struct TPtrs { const float* s[4]; bf16* d[4]; };

__global__ void transpose4(TPtrs p) {
    __shared__ bf16 t[32][33];
    const float* src = p.s[blockIdx.z];
    bf16*        dst = p.d[blockIdx.z];
    const int tx = threadIdx.x, ty = threadIdx.y;
    const int x  = blockIdx.x * 32 + tx;
    const int y0 = blockIdx.y * 32 + ty;
#pragma unroll
    for (int i = 0; i < 32; i += 8)
        t[ty + i][tx] = (bf16)src[(size_t)(y0 + i) * 1024 + x];
    __syncthreads();
    const int xo = blockIdx.y * 32 + tx;   // k index
    const int yo = blockIdx.x * 32 + ty;   // n index
#pragma unroll
    for (int i = 0; i < 32; i += 8)
        dst[(size_t)(yo + i) * 1024 + xo] = t[tx][ty + i];
}

// ----------------------------------------------- fp32 -> bf16 convert pass
// one thread per 8 elements: 2x float4 load, 1x 16B store. Memory-bound.
__global__ __launch_bounds__(256) void cvt_kernel(
    const float* __restrict__ src, bf16* __restrict__ dst)
{
    const size_t i = (size_t)blockIdx.x * 256 + threadIdx.x;  // per 8 elems
    const float4* s = (const float4*)src + 2 * i;
    float4 a = s[0];
    float4 b = s[1];
    bf16x8 h;
    h[0] = (bf16)a.x; h[1] = (bf16)a.y; h[2] = (bf16)a.z; h[3] = (bf16)a.w;
    h[4] = (bf16)b.x; h[5] = (bf16)b.y; h[6] = (bf16)b.z; h[7] = (bf16)b.w;
    *(bf16x8*)(dst + 8 * i) = h;
}

// ---------------------------------------------------- GEMM, all-bf16 (m97)
// C[M,N] = act(A[M,K] @ Bt[N,K]^T + bias[N]); act=1 -> phi(x)=elu(x)+1
__global__ __launch_bounds__(256) void gemm_bt_kernel(
    const bf16* __restrict__ A, const bf16* __restrict__ Bt,
    const float* __restrict__ bias, bf16* __restrict__ C,
    int M, int N, int K, int act)
{
    __shared__ bf16 As[128 * 32];
    __shared__ bf16 Bs[128 * 32];

    const int tid  = threadIdx.x;
    const int wave = tid >> 6;
    const int lane = tid & 63;
    const int m0 = blockIdx.y * 128;
    const int n0 = blockIdx.x * 128;
    const int wm = (wave >> 1) * 64;
    const int wn = (wave & 1) * 64;
    const int fr = lane & 15;
    const int fk = (lane >> 4) * 8;

    f32x4 acc[4][4] = {};

    const int c0 = wave * 64 + lane;
    const int c1 = c0 + 256;
    const int rA0 = c0 >> 2, kA0 = (c0 & 3) * 8;
    const int rA1 = c1 >> 2, kA1 = (c1 & 3) * 8;
    const bf16* gA0 = A  + (size_t)(m0 + rA0) * K + kA0;
    const bf16* gA1 = A  + (size_t)(m0 + rA1) * K + kA1;
    const bf16* gB0 = Bt + (size_t)(n0 + rA0) * K + kA0;
    const bf16* gB1 = Bt + (size_t)(n0 + rA1) * K + kA1;
    char* lA0 = (char*)As + (size_t)(wave * 64) * 16;
    char* lA1 = lA0 + 4096;
    char* lB0 = (char*)Bs + (size_t)(wave * 64) * 16;
    char* lB1 = lB0 + 4096;

    for (int kt = 0; kt < K; kt += 32) {
        async_ld16(gA0 + kt, lA0);
        async_ld16(gA1 + kt, lA1);
        async_ld16(gB0 + kt, lB0);
        async_ld16(gB1 + kt, lB1);
        __syncthreads();
        bf16x8 af[4], bfr[4];
#pragma unroll
        for (int i = 0; i < 4; ++i)
            af[i] = *(const bf16x8*)&As[(wm + i * 16 + fr) * 32 + fk];
#pragma unroll
        for (int j = 0; j < 4; ++j)
            bfr[j] = *(const bf16x8*)&Bs[(wn + j * 16 + fr) * 32 + fk];
#pragma unroll
        for (int i = 0; i < 4; ++i)
#pragma unroll
            for (int j = 0; j < 4; ++j)
                acc[i][j] = __builtin_amdgcn_mfma_f32_16x16x32_bf16(
                    af[i], bfr[j], acc[i][j], 0, 0, 0);
        __syncthreads();
    }

    // epilogue: D[row=(lane>>4)*4+r][col=lane&15] per 16x16 tile
#pragma unroll
    for (int j = 0; j < 4; ++j) {
        const int col = n0 + wn + j * 16 + fr;
        const float bb = bias[col];
#pragma unroll
        for (int i = 0; i < 4; ++i) {
            const int row = m0 + wm + i * 16 + (lane >> 4) * 4;
#pragma unroll
            for (int r = 0; r < 4; ++r) {
                float x = acc[i][j][r] + bb;
                if (act) x = (x > 0.0f) ? (x + 1.0f) : __expf(x);
                C[(size_t)(row + r) * N + col] = (bf16)x;
            }
        }
    }
}

// ------------------------------------- GEMM, bf16 in, OUTPUT = fp32 (O-proj)
__global__ __launch_bounds__(256) void gemm_bt_f32out_kernel(
    const bf16* __restrict__ A, const bf16* __restrict__ Bt,
    const float* __restrict__ bias, float* __restrict__ C,
    int M, int N, int K)
{
    __shared__ bf16 As[128 * 32];
    __shared__ bf16 Bs[128 * 32];

    const int tid  = threadIdx.x;
    const int wave = tid >> 6;
    const int lane = tid & 63;
    const int m0 = blockIdx.y * 128;
    const int n0 = blockIdx.x * 128;
    const int wm = (wave >> 1) * 64;
    const int wn = (wave & 1) * 64;
    const int fr = lane & 15;
    const int fk = (lane >> 4) * 8;

    f32x4 acc[4][4] = {};

    const int c0 = wave * 64 + lane;
    const int c1 = c0 + 256;
    const int rA0 = c0 >> 2, kA0 = (c0 & 3) * 8;
    const int rA1 = c1 >> 2, kA1 = (c1 & 3) * 8;
    const bf16* gA0 = A  + (size_t)(m0 + rA0) * K + kA0;
    const bf16* gA1 = A  + (size_t)(m0 + rA1) * K + kA1;
    const bf16* gB0 = Bt + (size_t)(n0 + rA0) * K + kA0;
    const bf16* gB1 = Bt + (size_t)(n0 + rA1) * K + kA1;
    char* lA0 = (char*)As + (size_t)(wave * 64) * 16;
    char* lA1 = lA0 + 4096;
    char* lB0 = (char*)Bs + (size_t)(wave * 64) * 16;
    char* lB1 = lB0 + 4096;

    for (int kt = 0; kt < K; kt += 32) {
        async_ld16(gA0 + kt, lA0);
        async_ld16(gA1 + kt, lA1);
        async_ld16(gB0 + kt, lB0);
        async_ld16(gB1 + kt, lB1);
        __syncthreads();
        bf16x8 af[4], bfr[4];
#pragma unroll
        for (int i = 0; i < 4; ++i)
            af[i] = *(const bf16x8*)&As[(wm + i * 16 + fr) * 32 + fk];
#pragma unroll
        for (int j = 0; j < 4; ++j)
            bfr[j] = *(const bf16x8*)&Bs[(wn + j * 16 + fr) * 32 + fk];
#pragma unroll
        for (int i = 0; i < 4; ++i)
#pragma unroll
            for (int j = 0; j < 4; ++j)
                acc[i][j] = __builtin_amdgcn_mfma_f32_16x16x32_bf16(
                    af[i], bfr[j], acc[i][j], 0, 0, 0);
        __syncthreads();
    }

#pragma unroll
    for (int j = 0; j < 4; ++j) {
        const int col = n0 + wn + j * 16 + fr;
        const float bb = bias[col];
#pragma unroll
        for (int i = 0; i < 4; ++i) {
            const int row = m0 + wm + i * 16 + (lane >> 4) * 4;
#pragma unroll
            for (int r = 0; r < 4; ++r)
                C[(size_t)(row + r) * N + col] = acc[i][j][r] + bb;
        }
    }
}

// -------------------------------------------------- kv partial accumulation
__global__ __launch_bounds__(256) void kv_partial_kernel(
    const bf16* __restrict__ Kb, const bf16* __restrict__ V,
    float* __restrict__ kv_part, float* __restrict__ ksum_part)
{
    const int bh = blockIdx.y;
    const int b  = bh >> 4;
    const int h  = bh & 15;
    const int tc = blockIdx.x;
    const int TC = T_ / 8;           // 512
    const int t0 = tc * TC;

    __shared__ float kb[8][64];
    __shared__ float vb[8][64];

    const int tid = threadIdx.x;
    const int dvq = tid >> 4;
    const int dkq = tid & 15;
    const int lr  = tid >> 5;
    const int lc  = (tid & 31) << 1;

    float acc[4][4] = {};
    float ksacc = 0.0f;

    for (int tt0 = 0; tt0 < TC; tt0 += 8) {
        const size_t base = ((size_t)(b * T_) + t0 + tt0 + lr) * 1024 + h * 64 + lc;
        bf16x2 k2 = *(const bf16x2*)&Kb[base];
        bf16x2 v2 = *(const bf16x2*)&V[base];
        kb[lr][lc] = (float)k2[0]; kb[lr][lc + 1] = (float)k2[1];
        vb[lr][lc] = (float)v2[0]; vb[lr][lc + 1] = (float)v2[1];
        __syncthreads();
#pragma unroll
        for (int tt = 0; tt < 8; ++tt) {
            float4 vv = *(const float4*)&vb[tt][dvq * 4];
            float4 kk = *(const float4*)&kb[tt][dkq * 4];
            float va[4] = {vv.x, vv.y, vv.z, vv.w};
            float ka[4] = {kk.x, kk.y, kk.z, kk.w};
#pragma unroll
            for (int i = 0; i < 4; ++i)
#pragma unroll
                for (int j = 0; j < 4; ++j)
                    acc[i][j] += va[i] * ka[j];
        }
        if (tid < 64) {
#pragma unroll
            for (int tt = 0; tt < 8; ++tt) ksacc += kb[tt][tid];
        }
        __syncthreads();
    }

    float* kvp = kv_part + ((size_t)tc * 64 + bh) * 4096;
#pragma unroll
    for (int i = 0; i < 4; ++i) {
        float4 w = make_float4(acc[i][0], acc[i][1], acc[i][2], acc[i][3]);
        *(float4*)&kvp[(dvq * 4 + i) * 64 + dkq * 4] = w;
    }
    if (tid < 64)
        ksum_part[((size_t)tc * 64 + bh) * 64 + tid] = ksacc;
}

// ------------------------------------------------------------- kv reduction
__global__ __launch_bounds__(256) void kv_reduce_kernel(
    const float* __restrict__ kv_part, const float* __restrict__ ksum_part,
    bf16* __restrict__ kvb, float* __restrict__ ksum)
{
    const int bh = blockIdx.x;
    const int tid = threadIdx.x;
    for (int e = tid; e < 4096; e += 256) {
        float s = 0.0f;
#pragma unroll
        for (int tc = 0; tc < 8; ++tc)
            s += kv_part[((size_t)tc * 64 + bh) * 4096 + e];
        kvb[(size_t)bh * 4096 + e] = (bf16)s;
    }
    if (tid < 64) {
        float s = 0.0f;
#pragma unroll
        for (int tc = 0; tc < 8; ++tc)
            s += ksum_part[((size_t)tc * 64 + bh) * 64 + tid];
        ksum[bh * 64 + tid] = s;
    }
}

// ------------------------------------------------------------------ attn
__global__ __launch_bounds__(256) void attn_kernel(
    const bf16* __restrict__ Q, const bf16* __restrict__ kvb,
    const float* __restrict__ ksum, bf16* __restrict__ attn)
{
    const int bh = blockIdx.y;
    const int b  = bh >> 4;
    const int h  = bh & 15;
    const int t0 = blockIdx.x * 128;

    __shared__ bf16 As[128 * 64];
    __shared__ bf16 Bs[64 * 64];
    __shared__ float ksum_s[64];
    __shared__ float norm_s[128];

    const int tid  = threadIdx.x;
    const int wave = tid >> 6;
    const int lane = tid & 63;

    const bf16* Qbase = Q + ((size_t)(b * T_) + t0) * 1024 + h * 64;

#pragma unroll
    for (int r2 = 0; r2 < 4; ++r2) {
        const int c   = r2 * 256 + wave * 64 + lane;
        const int row = c >> 3;
        const int ko  = (c & 7) * 8;
        char* l = (char*)As + (size_t)(r2 * 256 + wave * 64) * 16;
        async_ld16(Qbase + (size_t)row * 1024 + ko, l);
    }
    {
        const float4* src = (const float4*)(kvb + (size_t)bh * 4096);
        float4* dst = (float4*)Bs;
        for (int e = tid; e < 512; e += 256) dst[e] = src[e];
    }
    if (tid < 64) ksum_s[tid] = ksum[bh * 64 + tid];
    __syncthreads();

    if (tid < 128) {
        const bf16x8* qp = (const bf16x8*)(Qbase + (size_t)tid * 1024);
        float s = 0.0f;
#pragma unroll
        for (int u = 0; u < 8; ++u) {
            bf16x8 v = qp[u];
#pragma unroll
            for (int e = 0; e < 8; ++e) s += (float)v[e] * ksum_s[u * 8 + e];
        }
        norm_s[tid] = 1.0f / (s + EPS_);
    }
    __syncthreads();

    const int fr  = lane & 15;
    const int fkq = lane >> 4;
    f32x4 acc[2][4] = {};
#pragma unroll
    for (int ks = 0; ks < 2; ++ks) {
        bf16x8 af[2], bfr[4];
#pragma unroll
        for (int i = 0; i < 2; ++i)
            af[i] = *(const bf16x8*)&As[(wave * 32 + i * 16 + fr) * 64 + ks * 32 + fkq * 8];
#pragma unroll
        for (int j = 0; j < 4; ++j)
            bfr[j] = *(const bf16x8*)&Bs[(j * 16 + fr) * 64 + ks * 32 + fkq * 8];
#pragma unroll
        for (int i = 0; i < 2; ++i)
#pragma unroll
            for (int j = 0; j < 4; ++j)
                acc[i][j] = __builtin_amdgcn_mfma_f32_16x16x32_bf16(
                    af[i], bfr[j], acc[i][j], 0, 0, 0);
    }

    bf16* out = attn + ((size_t)(b * T_) + t0) * 1024 + h * 64;
#pragma unroll
    for (int i = 0; i < 2; ++i)
#pragma unroll
        for (int j = 0; j < 4; ++j)
#pragma unroll
            for (int r = 0; r < 4; ++r) {
                const int row = wave * 32 + i * 16 + fkq * 4 + r;
                const int col = j * 16 + fr;
                out[(size_t)row * 1024 + col] = (bf16)(acc[i][j][r] * norm_s[row]);
            }
}

// ---------------------------------------------------------------- launcher
// inputs fp32, OUTPUT fp32 (64 MiB). ws (<=48.7 MiB):
//  [0,8)   WT bf16 (WqT/WkT/WvT/WoT)
//  [8,40)  CVT slot (bf16 activation; later reused as ATTN)
//  [40,48) kv_part fp32 | [48,+128K) ksum_part | +512K kvb | +16K ksum
// d_out doubles as scratch: KB in [0,32), VB in [32,64); Qb reuses [0,32)
// after kv; final O-GEMM overwrites all 64 MiB with fp32 output.
extern "C" void kernel_launch(void* const* d_in, const int* in_sizes, int n_in,
                              void* d_out, int out_size, void* d_ws, size_t ws_size,
                              hipStream_t stream) {
    const float* query = (const float*)d_in[0];
    const float* key_  = (const float*)d_in[1];
    const float* value = (const float*)d_in[2];
    const float* Wq = (const float*)d_in[3];
    const float* bq = (const float*)d_in[4];
    const float* Wk = (const float*)d_in[5];
    const float* bk = (const float*)d_in[6];
    const float* Wv = (const float*)d_in[7];
    const float* bv = (const float*)d_in[8];
    const float* Wo = (const float*)d_in[9];
    const float* bo = (const float*)d_in[10];

    char* ws = (char*)d_ws;
    char* out8 = (char*)d_out;
    const size_t MB = 1024 * 1024;
    bf16* WqT = (bf16*)(ws + 0 * MB);
    bf16* WkT = (bf16*)(ws + 2 * MB);
    bf16* WvT = (bf16*)(ws + 4 * MB);
    bf16* WoT = (bf16*)(ws + 6 * MB);
    bf16* CVT = (bf16*)(ws + 8 * MB);                    // 32 MiB, reused 3x
    float* kv_part   = (float*)(ws + 40 * MB);           // 8 MiB
    float* ksum_part = (float*)(ws + 48 * MB);           // 128 KiB
    bf16*  kvb  = (bf16*)(ws + 48 * MB + 128 * 1024);    // 512 KiB
    float* ksum = (float*)(ws + 48 * MB + 640 * 1024);   // 16 KiB

    bf16* KB   = (bf16*)out8;                            // d_out [0,32)
    bf16* VB   = (bf16*)(out8 + 32 * MB);                // d_out [32,64)
    bf16* Qb   = (bf16*)out8;                            // reused after kv
    bf16* ATTN = CVT;                                    // reuses CVT slot

    TPtrs tp;
    tp.s[0] = Wq;  tp.s[1] = Wk;  tp.s[2] = Wv;  tp.s[3] = Wo;
    tp.d[0] = WqT; tp.d[1] = WkT; tp.d[2] = WvT; tp.d[3] = WoT;
    transpose4<<<dim3(32, 32, 4), dim3(32, 8, 1), 0, stream>>>(tp);

    const int CVT_BLOCKS = M_ * 1024 / 8 / 256;          // 8192

    cvt_kernel<<<CVT_BLOCKS, 256, 0, stream>>>(key_, CVT);
    gemm_bt_kernel<<<dim3(8, 128), 256, 0, stream>>>(CVT, WkT, bk, KB, M_, 1024, 1024, 1);

    cvt_kernel<<<CVT_BLOCKS, 256, 0, stream>>>(value, CVT);
    gemm_bt_kernel<<<dim3(8, 128), 256, 0, stream>>>(CVT, WvT, bv, VB, M_, 1024, 1024, 0);

    kv_partial_kernel<<<dim3(8, 64), 256, 0, stream>>>(KB, VB, kv_part, ksum_part);
    kv_reduce_kernel<<<dim3(64), 256, 0, stream>>>(kv_part, ksum_part, kvb, ksum);

    cvt_kernel<<<CVT_BLOCKS, 256, 0, stream>>>(query, CVT);
    gemm_bt_kernel<<<dim3(8, 128), 256, 0, stream>>>(CVT, WqT, bq, Qb, M_, 1024, 1024, 1);

    attn_kernel<<<dim3(32, 64), 256, 0, stream>>>(Qb, kvb, ksum, ATTN);

    gemm_bt_f32out_kernel<<<dim3(8, 128), 256, 0, stream>>>(ATTN, WoT, bo, (float*)d_out, M_, 1024, 1024);
}